// Round 13
// baseline (337.462 us; speedup 1.0000x reference)
//
#include <hip/hip_runtime.h>

// Problem constants (fixed by reference)
#define CI    16
#define CO    16
#define HID   256
#define KPAD  288    // 256 + 32; k==256 row carries b2 (VALU-free bias), rest 0
#define NKK   9      // KPAD/32 MFMA K-steps (B side; W2b layout)
#define NKH   8      // kk frags held in LDS (kk=8 pad frag synthesized in regs)
#define NCH   144    // CI*9 columns per output channel
#define IMGH  128
#define IMGW  128
#define PTS   68     // shPatchT row stride in SHORTS (136 B: 8B-aligned, <=4-way)
#define KKSTR (NCH * 32)        // shorts per kk block  = 4608
#define OSTRS (NKK * NCH * 32)  // shorts per o         = 41472
#define PSTR  1536              // shorts per pass step (3 n-tiles * 512)

typedef float f32x4  __attribute__((ext_vector_type(4)));
typedef float f32x2  __attribute__((ext_vector_type(2)));
typedef short bf16x8 __attribute__((ext_vector_type(8)));

__device__ __host__ __forceinline__ short f2bf(float f) {
  union { float f; unsigned u; } c; c.f = f;
  unsigned b = c.u + 0x7FFFu + ((c.u >> 16) & 1u);   // RNE
  return (short)(b >> 16);
}

// ---------------------------------------------------------------------------
// Prep: W2 [256][2304] fp32 (+ b2[2304]) -> W2b [o][kk:9][n:144][k:32] bf16,
// K padded to 288 (row 256 = b2, rows 257..287 = 0).
// grid = 36 col-blocks * 9 kk = 324 blocks x 256 threads.
// ---------------------------------------------------------------------------
__global__ void prep_w2(const float* __restrict__ W2, const float* __restrict__ b2,
                        short* __restrict__ W2b) {
  __shared__ float tile[32][65];
  const int kk = blockIdx.x % NKK;
  const int colbase = (blockIdx.x / NKK) * 64;
  const int tid = threadIdx.x;

  for (int e = tid; e < 2048; e += 256) {
    int klr = e >> 6;          // 0..31
    int cc  = e & 63;
    int col = colbase + cc;
    float v;
    if (kk < 8) v = W2[(kk * 32 + klr) * (CO * NCH) + col];
    else        v = (klr == 0) ? b2[col] : 0.f;
    tile[klr][cc] = v;
  }
  __syncthreads();
  for (int e = tid; e < 2048; e += 256) {
    int cc = e >> 5;           // 0..63
    int kl = e & 31;
    int col = colbase + cc;
    int o = col / NCH;
    int n = col - o * NCH;
    W2b[(((o * NKK + kk) * NCH + n) << 5) + kl] = f2bf(tile[kl][cc]);
  }
}

// Macros keep the rotation as straight-line code on plain locals (NO arrays
// passed by reference -- R9's helper-by-reference caused scratch demotion).
#define LOADB(BUF, PTR)                                   \
  { _Pragma("unroll")                                     \
    for (int j = 0; j < 3; ++j)                           \
      BUF[j] = *(const bf16x8*)&(PTR)[j << 9]; }

#define MFMAK(KK, BUF)                                    \
  { const short* hp = shHf + ((KK) << 9) + (lane << 3);   \
    _Pragma("unroll")                                     \
    for (int ms = 0; ms < 4; ++ms) {                      \
      bf16x8 af = *(const bf16x8*)&hp[ms * (NKH << 9)];   \
      _Pragma("unroll")                                   \
      for (int j = 0; j < 3; ++j)                         \
        acc[ms][j] = __builtin_amdgcn_mfma_f32_16x16x32_bf16( \
            af, BUF[j], acc[ms][j], 0, 0, 0);             \
    } }

#define MFMA8(BUF)                                        \
  { _Pragma("unroll")                                     \
    for (int ms = 0; ms < 4; ++ms)                        \
      _Pragma("unroll")                                   \
      for (int j = 0; j < 3; ++j)                         \
        acc[ms][j] = __builtin_amdgcn_mfma_f32_16x16x32_bf16( \
            af8, BUF[j], acc[ms][j], 0, 0, 0); }

// ---------------------------------------------------------------------------
// Main fused kernel, v13 = R12 (129 us) + depth-2 B pipeline:
//  3 rotating buffers (bA,bB,bC), distance-2 prefetch, written as 9
//  straight-line bodies per pass; bodies 7-8 prefetch the NEXT (pass/oj)
//  iteration's kk0/kk1 so the pipeline never drains (epilogue overlaps the
//  next pass's leading loads). Clamped to self on the final iteration.
// One block = 64 px of one image row; 4 waves; wave w owns channels
// {w, w+4, w+8, w+12}; M=64/wave, N=144/channel in 3 passes of 3 n-tiles,
// K=288 (b2 as K-row; kk=8 A-frag af8 is a register constant).
// shHf kk0..7 in MFMA fragment order (conflict-free ds_read_b128);
// shPatchT [n][px] bf16 stride 68 (one b64 = 4 r-values). LDS 51.1 KB.
// grid = 4 batches * 128 rows * 2 half-rows = 1024 blocks x 256 threads.
// ---------------------------------------------------------------------------
__global__ __launch_bounds__(256, 3)
void ngconv_main(const float* __restrict__ in, const float* __restrict__ foa,
                 const float* __restrict__ W1, const float* __restrict__ b1,
                 const short* __restrict__ W2b, float* __restrict__ out) {
  __shared__ short shHf[32 * 512];        // 32 frags (ms,kk 0..7) = 32.8 KB
  __shared__ short shPatchT[NCH * PTS];   // patch matrix [n][px] bf16, 19.6 KB

  const int tid  = threadIdx.x;
  const int lane = tid & 63;
  const int wv   = tid >> 6;
  const int c15  = lane & 15;
  const int quad = lane >> 4;

  const int blk = blockIdx.x;
  const int b   = blk >> 8;
  const int rem = blk & 255;
  const int y   = rem >> 1;
  const int x0  = (rem & 1) << 6;

  const float fx  = foa[b * 2 + 0];
  const float fy  = foa[b * 2 + 1];
  const float dyv = (float)y - fy;

  const int ry0 = (y == 0) ? 1 : (y - 1);
  const int ry2 = (y == IMGH - 1) ? (IMGH - 2) : (y + 1);

  // ---- shPatchT[n][px] (bf16): patch value for column n, pixel px
  for (int e = tid; e < NCH * 64; e += 256) {
    int n  = e >> 6;                  // 0..143
    int px = e & 63;
    int i = n / 9, q = n - i * 9;
    int dyr = q / 3, dx = q - dyr * 3;
    int ryr = (dyr == 0) ? ry0 : ((dyr == 1) ? y : ry2);
    int x = x0 + px + dx - 1;
    x = (x < 0) ? 1 : ((x > IMGW - 1) ? (IMGW - 2) : x);   // reflect
    shPatchT[n * PTS + px] = f2bf(in[((b * CI + i) * IMGH + ryr) * IMGW + x]);
  }

  // ---- shHf: H in fragment order, kk=0..7 only. frag(ms,kk) = A[16px][32k];
  // lane slot (c15=px, quad=k-octet). 64 px x 32 k-slots = 2048 = 8 exact its.
  for (int g = tid; g < 64 * 32; g += 256) {
    int px = g & 63;
    int ks = g >> 6;                  // 0..31 -> k0 = ks*8 < 256
    int k0 = ks << 3;
    float dxv = (float)(x0 + px) - fx;
    short hv[8];
    #pragma unroll
    for (int j = 0; j < 8; ++j) {
      int k = k0 + j;
      float h = fmaxf(fmaf(dxv, W1[k], fmaf(dyv, W1[HID + k], b1[k])), 0.f);
      hv[j] = f2bf(h);
    }
    int ms = px >> 4;
    int kk = k0 >> 5;
    int lslot = ((k0 & 31) >> 3) * 16 + (px & 15);   // quad*16 + c15
    *(bf16x8*)&shHf[((ms * NKH + kk) << 9) + (lslot << 3)] = *(bf16x8*)hv;
  }

  // ---- kk=8 pad fragment, constant, in registers: k=256 -> 1.0 (b2 row)
  bf16x8 af8 = (bf16x8){0, 0, 0, 0, 0, 0, 0, 0};
  if (quad == 0) af8[0] = (short)0x3F80;   // bf16 1.0

  __syncthreads();

  const short* Bo0 = W2b + wv * OSTRS + (c15 << 5) + (quad << 3);

  // steady-state pipeline registers (loop-carried across pass/oj boundaries):
  // at every pass top, bA = this pass's kk0, bB = kk1.
  bf16x8 bA[3], bB[3], bC[3];
  LOADB(bA, Bo0);
  LOADB(bB, Bo0 + KKSTR);

  // ---- main loop: 4 output channels per wave, N in three passes of 3
  #pragma unroll 1
  for (int oj = 0; oj < 4; ++oj) {
    const short* Bo = Bo0 + oj * (4 * OSTRS);   // o = wv + oj*4

    // per-oj partial sums (accumulate across all 3 passes; tree at the end)
    f32x2 P2[8];
    #pragma unroll
    for (int t = 0; t < 8; ++t) P2[t] = (f32x2){0.f, 0.f};

    #pragma unroll 1
    for (int pass = 0; pass < 3; ++pass) {
      const short* Bp = Bo + pass * PSTR;
      // next iteration's stream base (clamped to self at the very end)
      const short* BpN = (pass < 2) ? (Bp + PSTR)
                        : ((oj < 3) ? (Bp - 2 * PSTR + 4 * OSTRS) : Bp);

      f32x4 acc[4][3];
      #pragma unroll
      for (int ms = 0; ms < 4; ++ms)
        #pragma unroll
        for (int j = 0; j < 3; ++j)
          acc[ms][j] = (f32x4){0.f, 0.f, 0.f, 0.f};

      // 9 bodies, 3-buffer rotation, distance-2; bodies 7-8 prefetch BpN.
      LOADB(bC, Bp + 2 * KKSTR);  MFMAK(0, bA)
      LOADB(bA, Bp + 3 * KKSTR);  MFMAK(1, bB)
      LOADB(bB, Bp + 4 * KKSTR);  MFMAK(2, bC)
      LOADB(bC, Bp + 5 * KKSTR);  MFMAK(3, bA)
      LOADB(bA, Bp + 6 * KKSTR);  MFMAK(4, bB)
      LOADB(bB, Bp + 7 * KKSTR);  MFMAK(5, bC)
      LOADB(bC, Bp + 8 * KKSTR);  MFMAK(6, bA)
      LOADB(bA, BpN);             MFMAK(7, bB)
      LOADB(bB, BpN + KKSTR);     MFMA8(bC)

      // ---- per-pass patch contraction into P2 (b2 already in acc).
      // lane needs px = ms*16 + quad*4 + r; [n][px] bf16 -> ONE b64 = 4 vals.
      #pragma unroll
      for (int j = 0; j < 3; ++j) {
        int n15 = ((pass * 3 + j) << 4) + c15;
        const short* prow = &shPatchT[n15 * PTS + (quad << 2)];
        #pragma unroll
        for (int ms = 0; ms < 4; ++ms) {
          uint2 u = *(const uint2*)&prow[ms * 16];        // ds_read_b64
          float p0 = __uint_as_float(u.x << 16);
          float p1 = __uint_as_float(u.x & 0xFFFF0000u);
          float p2 = __uint_as_float(u.y << 16);
          float p3 = __uint_as_float(u.y & 0xFFFF0000u);
          f32x2 a01 = {acc[ms][j][0], acc[ms][j][1]};
          f32x2 a23 = {acc[ms][j][2], acc[ms][j][3]};
          P2[ms * 2 + 0] += a01 * (f32x2){p0, p1};        // v_pk_fma_f32 cand.
          P2[ms * 2 + 1] += a23 * (f32x2){p2, p3};
        }
      }
    }

    // ---- ONE reduce-scatter tree per oj.
    // final P[0] at lane = column sum for px=(c15>>2)*16+quad*4+(c15&3)
    float P[16];
    #pragma unroll
    for (int t = 0; t < 16; ++t) P[t] = P2[t >> 1][t & 1];
    #pragma unroll
    for (int m = 8; m >= 1; m >>= 1) {
      const bool hi = (c15 & m) != 0;
      #pragma unroll
      for (int j = 0; j < m; ++j) {
        float keep = hi ? P[j + m] : P[j];
        float send = hi ? P[j] : P[j + m];
        float recv = __shfl_xor(send, m, 64);
        P[j] = keep + recv;
      }
    }

    const int o = wv + oj * 4;
    const int x = x0 + (c15 >> 2) * 16 + quad * 4 + (c15 & 3);
    out[((b * CO + o) * IMGH + y) * IMGW + x] = P[0];
  }
}

// ---------------------------------------------------------------------------
extern "C" void kernel_launch(void* const* d_in, const int* in_sizes, int n_in,
                              void* d_out, int out_size, void* d_ws, size_t ws_size,
                              hipStream_t stream) {
  const float* in  = (const float*)d_in[0];   // [4,16,128,128]
  const float* foa = (const float*)d_in[1];   // [4,2]
  const float* W1  = (const float*)d_in[2];   // [2,256]
  const float* b1  = (const float*)d_in[3];   // [256]
  const float* W2  = (const float*)d_in[4];   // [256,2304]
  const float* b2  = (const float*)d_in[5];   // [2304]
  float* out = (float*)d_out;
  short* W2b = (short*)d_ws;                  // 16*9*144*32 bf16 = 1.33 MB

  prep_w2<<<324, 256, 0, stream>>>(W2, b2, W2b);
  ngconv_main<<<1024, 256, 0, stream>>>(in, foa, W1, b1, W2b, out);
}